// Round 1
// baseline (28.552 us; speedup 1.0000x reference)
//
#include <hip/hip_runtime.h>
#include <math.h>

// Problem constants
#define BATCH   32
#define DIMN    96          // every spatial dim is 96
#define KCOMP   64          // number of Gaussian components
#define NUM_IN  (DIMN*DIMN) // 9216
#define NUM_OUT (DIMN*DIMN) // 9216

// Workspace layout (floats):
//   fac[4][KCOMP][DIMN]  -- factor tables, k-major. dim0,1 = input dims; dim2,3 = output dims.
//                           dim 2 is pre-scaled by weights[k].
//   y[BATCH][KCOMP]      -- x projected onto input Gaussians
#define FAC_ELEMS (4 * KCOMP * DIMN)   // 24576
#define Y_OFFSET  FAC_ELEMS            // 24576
#define WS_FLOATS (FAC_ELEMS + BATCH * KCOMP)

// ---------------------------------------------------------------------------
// Kernel 1: build factor tables.
// fac[dim][k][i] = exp(-(grid_i - mu[k,dim])^2 / (2*exp(log_var[k,dim])))
// grid_i = i/95 (linspace(0,1,96)).  dim==2 additionally scaled by weights[k].
// ---------------------------------------------------------------------------
__global__ __launch_bounds__(256) void k_factors(const float* __restrict__ mus,
                                                 const float* __restrict__ log_vars,
                                                 const float* __restrict__ weights,
                                                 float* __restrict__ fac) {
    int idx = blockIdx.x * 256 + threadIdx.x;
    if (idx >= FAC_ELEMS) return;
    int dim = idx / (KCOMP * DIMN);
    int rem = idx - dim * (KCOMP * DIMN);
    int k   = rem / DIMN;
    int i   = rem - k * DIMN;

    float mu  = mus[k * 4 + dim];
    float var = expf(log_vars[k * 4 + dim]);
    float g   = (float)i * (1.0f / 95.0f);
    float t   = g - mu;
    float val = expf(-(t * t) / (2.0f * var));
    if (dim == 2) val *= weights[k];
    fac[idx] = val;
}

// ---------------------------------------------------------------------------
// Kernel 2: y[b,k] = sum_{a,d} x[b, a*96+d] * f0[k][a] * f1[k][d]
// One wave per (b, k-pair): wave wid handles b = wid>>5, k = wid&31 and k+32.
// Lanes stride the 9216 elements of x[b] coalesced (i = lane + 64*j).
// f0 reads are wave-broadcast (a uniform-ish); f1 reads lane-consecutive.
// ---------------------------------------------------------------------------
__global__ __launch_bounds__(256) void k_xproj(const float* __restrict__ x,
                                               const float* __restrict__ fac,
                                               float* __restrict__ y) {
    int wid  = blockIdx.x * 4 + (threadIdx.x >> 6);   // 0..1023
    int lane = threadIdx.x & 63;
    int b  = wid >> 5;          // 0..31
    int kk = wid & 31;          // 0..31 -> handles kk and kk+32

    const float* F0a = fac + (0 * KCOMP + kk)      * DIMN;
    const float* F0b = fac + (0 * KCOMP + kk + 32) * DIMN;
    const float* F1a = fac + (1 * KCOMP + kk)      * DIMN;
    const float* F1b = fac + (1 * KCOMP + kk + 32) * DIMN;
    const float* xb  = x + b * NUM_IN;

    float s0 = 0.0f, s1 = 0.0f;
    int i = lane;       // flat index into x[b]
    int a = 0;          // i / 96  (lane < 96 so a starts at 0)
    int d = lane;       // i % 96
    #pragma unroll 4
    for (int j = 0; j < NUM_IN / 64; ++j) {   // 144 iters
        float xv = xb[i];
        s0 = fmaf(xv * F0a[a], F1a[d], s0);
        s1 = fmaf(xv * F0b[a], F1b[d], s1);
        i += 64;
        d += 64;
        if (d >= DIMN) { d -= DIMN; ++a; }
    }
    // full-wave butterfly reduction (deterministic)
    #pragma unroll
    for (int off = 32; off > 0; off >>= 1) {
        s0 += __shfl_xor(s0, off, 64);
        s1 += __shfl_xor(s1, off, 64);
    }
    if (lane == 0) {
        y[b * KCOMP + kk]      = s0;
        y[b * KCOMP + kk + 32] = s1;
    }
}

// ---------------------------------------------------------------------------
// Kernel 3: out[b, c*96+d] = bias[c*96+d] + sum_k y[b,k] * (w[k]*g0[k][c]) * g1[k][d]
// One thread per output element. y and g0 reads are wave-broadcast; g1 reads
// are lane-coalesced (d consecutive across lanes).  w already folded into g0.
// ---------------------------------------------------------------------------
__global__ __launch_bounds__(256) void k_out(const float* __restrict__ y,
                                             const float* __restrict__ fac,
                                             const float* __restrict__ bias,
                                             float* __restrict__ out) {
    int idx = blockIdx.x * 256 + threadIdx.x;
    if (idx >= BATCH * NUM_OUT) return;
    int b = idx / NUM_OUT;
    int o = idx - b * NUM_OUT;
    int c = o / DIMN;
    int d = o - c * DIMN;

    const float* G0 = fac + 2 * KCOMP * DIMN;   // pre-scaled by weights
    const float* G1 = fac + 3 * KCOMP * DIMN;
    const float* yb = y + b * KCOMP;

    float s = bias[o];
    #pragma unroll 8
    for (int k = 0; k < KCOMP; ++k) {
        s = fmaf(yb[k] * G0[k * DIMN + c], G1[k * DIMN + d], s);
    }
    out[idx] = s;
}

// ---------------------------------------------------------------------------
extern "C" void kernel_launch(void* const* d_in, const int* in_sizes, int n_in,
                              void* d_out, int out_size, void* d_ws, size_t ws_size,
                              hipStream_t stream) {
    const float* x        = (const float*)d_in[0];   // (32, 96, 96)
    const float* mus      = (const float*)d_in[1];   // (64, 4)
    const float* log_vars = (const float*)d_in[2];   // (64, 4)
    const float* weights  = (const float*)d_in[3];   // (64,)
    const float* bias     = (const float*)d_in[4];   // (9216,)
    float* out = (float*)d_out;                      // (32, 96, 96)

    float* fac = (float*)d_ws;            // FAC_ELEMS floats
    float* y   = fac + Y_OFFSET;          // BATCH*KCOMP floats

    // K1: factor tables (24576 elements)
    k_factors<<<(FAC_ELEMS + 255) / 256, 256, 0, stream>>>(mus, log_vars, weights, fac);

    // K2: y[b,k] — 1024 waves = 256 blocks of 4 waves
    k_xproj<<<(BATCH * 32) / 4, 256, 0, stream>>>(x, fac, y);

    // K3: outputs — one thread each
    k_out<<<(BATCH * NUM_OUT) / 256, 256, 0, stream>>>(y, fac, bias, out);
}

// Round 2
// 23.637 us; speedup vs baseline: 1.2079x; 1.2079x over previous
//
#include <hip/hip_runtime.h>
#include <math.h>

// Problem constants
#define BATCH   32
#define DIMN    96
#define KCOMP   64
#define NUM_IN  (DIMN*DIMN)   // 9216
#define NUM_OUT (DIMN*DIMN)   // 9216

// Workspace layout (floats):
//   G0[KCOMP][DIMN]  @ 0      -- out-dim-0 factor, pre-scaled by weights[k]
//   G1[KCOMP][DIMN]  @ 6144   -- out-dim-1 factor
//   Y [BATCH][KCOMP] @ 12288  -- x projected onto input Gaussians
#define G0_OFF 0
#define G1_OFF (KCOMP * DIMN)          // 6144
#define Y_OFF  (2 * KCOMP * DIMN)      // 12288

// ---------------------------------------------------------------------------
// Kernel 1 (fused): factor tables + Y projection.
//  - Blocks 0..47: each thread computes one element of G0/G1 (12288 total).
//  - All 256 blocks x 4 waves: wave wid handles (b = wid>>5, k = wid&31 and
//    k+32). Wave builds its four 96-entry input-dim factor rows in LDS
//    (~6 exps/lane), then strides x[b] coalesced, butterfly-reduces.
// ---------------------------------------------------------------------------
__global__ __launch_bounds__(256) void k_stage1(const float* __restrict__ x,
                                                const float* __restrict__ mus,
                                                const float* __restrict__ log_vars,
                                                const float* __restrict__ weights,
                                                float* __restrict__ ws) {
    int tid = threadIdx.x;

    // ---- Part A: output-dim factor tables (dims 2,3), 12288 elements ----
    if (blockIdx.x < 48) {
        int idx = blockIdx.x * 256 + tid;          // 0..12287
        int dim = idx / (KCOMP * DIMN);            // 0 -> dim2(G0), 1 -> dim3(G1)
        int rem = idx - dim * (KCOMP * DIMN);
        int k   = rem / DIMN;
        int i   = rem - k * DIMN;
        float mu  = mus[k * 4 + 2 + dim];
        float var = expf(log_vars[k * 4 + 2 + dim]);
        float t   = (float)i * (1.0f / 95.0f) - mu;
        float v   = expf(-(t * t) / (2.0f * var));
        if (dim == 0) v *= weights[k];             // fold weights into G0
        ws[idx] = v;
    }

    // ---- Part B: Y[b,k] ----
    __shared__ float F[4][4][DIMN];                // [wave][row][i], 6 KB
    int w    = tid >> 6;
    int lane = tid & 63;
    int wid  = blockIdx.x * 4 + w;                 // 0..1023
    int b    = wid >> 5;                           // 0..31
    int kk   = wid & 31;                           // handles kk, kk+32

    #pragma unroll
    for (int r = 0; r < 4; ++r) {                  // r0:k,d0 r1:k+32,d0 r2:k,d1 r3:k+32,d1
        int k   = (r & 1) ? kk + 32 : kk;
        int dim = r >> 1;
        float mu = mus[k * 4 + dim];
        float rv = 0.5f / expf(log_vars[k * 4 + dim]);   // 1/(2 var)
        for (int i = lane; i < DIMN; i += 64) {
            float t = (float)i * (1.0f / 95.0f) - mu;
            F[w][r][i] = expf(-(t * t) * rv);
        }
    }
    __syncthreads();

    const float* xb = x + b * NUM_IN;
    float s0 = 0.0f, s1 = 0.0f;
    int i = lane, a = 0, d = lane;
    #pragma unroll 4
    for (int j = 0; j < NUM_IN / 64; ++j) {        // 144 iters
        float xv = xb[i];
        s0 = fmaf(xv * F[w][0][a], F[w][2][d], s0);
        s1 = fmaf(xv * F[w][1][a], F[w][3][d], s1);
        i += 64; d += 64;
        if (d >= DIMN) { d -= DIMN; ++a; }
    }
    #pragma unroll
    for (int off = 32; off > 0; off >>= 1) {
        s0 += __shfl_xor(s0, off, 64);
        s1 += __shfl_xor(s1, off, 64);
    }
    if (lane == 0) {
        ws[Y_OFF + b * KCOMP + kk]      = s0;
        ws[Y_OFF + b * KCOMP + kk + 32] = s1;
    }
}

// ---------------------------------------------------------------------------
// Kernel 2: out[b, o] = bias[o] + sum_k Y[b,k] * G0[k][c] * G1[k][d]
// Block = 64 consecutive outputs x all 32 batch rows. Y staged in LDS (8 KB,
// broadcast reads). Per k-iter: 1 broadcast load (G0) + 1 coalesced load (G1)
// feed 8 FMAs per thread (8 batch rows per thread).
// ---------------------------------------------------------------------------
__global__ __launch_bounds__(256) void k_stage2(const float* __restrict__ ws,
                                                const float* __restrict__ bias,
                                                float* __restrict__ out) {
    __shared__ float Ys[BATCH * KCOMP];            // 8 KB
    int tid = threadIdx.x;
    #pragma unroll
    for (int idx = tid; idx < BATCH * KCOMP; idx += 256)
        Ys[idx] = ws[Y_OFF + idx];
    __syncthreads();

    int lane = tid & 63;
    int bg   = tid >> 6;                           // 0..3 -> batch rows bg*8..bg*8+7
    int o    = blockIdx.x * 64 + lane;             // 144 blocks * 64 = 9216
    int c    = o / DIMN;
    int d    = o - c * DIMN;

    const float* G0 = ws + G0_OFF;
    const float* G1 = ws + G1_OFF;

    float acc[8] = {0,0,0,0,0,0,0,0};
    #pragma unroll 4
    for (int k = 0; k < KCOMP; ++k) {
        float ww = G0[k * DIMN + c] * G1[k * DIMN + d];
        #pragma unroll
        for (int j = 0; j < 8; ++j)
            acc[j] = fmaf(Ys[(bg * 8 + j) * KCOMP + k], ww, acc[j]);
    }

    float bs = bias[o];
    #pragma unroll
    for (int j = 0; j < 8; ++j)
        out[(bg * 8 + j) * NUM_OUT + o] = acc[j] + bs;
}

// ---------------------------------------------------------------------------
extern "C" void kernel_launch(void* const* d_in, const int* in_sizes, int n_in,
                              void* d_out, int out_size, void* d_ws, size_t ws_size,
                              hipStream_t stream) {
    const float* x        = (const float*)d_in[0];   // (32, 96, 96)
    const float* mus      = (const float*)d_in[1];   // (64, 4)
    const float* log_vars = (const float*)d_in[2];   // (64, 4)
    const float* weights  = (const float*)d_in[3];   // (64,)
    const float* bias     = (const float*)d_in[4];   // (9216,)
    float* out = (float*)d_out;                      // (32, 96, 96)
    float* ws  = (float*)d_ws;

    k_stage1<<<256, 256, 0, stream>>>(x, mus, log_vars, weights, ws);
    k_stage2<<<NUM_OUT / 64, 256, 0, stream>>>(ws, bias, out);
}